// Round 1
// baseline (341.045 us; speedup 1.0000x reference)
//
#include <hip/hip_runtime.h>

typedef __bf16 bf16_t;
typedef bf16_t bf16x8 __attribute__((ext_vector_type(8)));
typedef bf16_t bf16x4 __attribute__((ext_vector_type(4)));
typedef float f32x4 __attribute__((ext_vector_type(4)));

#define F 512
#define NLAYERS 8
#define NLIL 8
#define TM 128
#define LSTR 520  // 512 + 8 bf16 pad: A-frag ds_read_b128 phase-optimal

// ---- pre-pass 1: Wbig [l][f][g] fp32 -> WbigT [l][g][f] bf16 (transpose+convert)
__global__ void transpose_wbig(const float* __restrict__ W, bf16_t* __restrict__ out) {
  __shared__ float tile[64][65];
  const int l = blockIdx.z;
  const int tf = blockIdx.x, tg = blockIdx.y;
  const float* Wl = W + (size_t)l * F * F;
  bf16_t* Ol = out + (size_t)l * F * F;
  const int tx = threadIdx.x & 63;
  const int ty = threadIdx.x >> 6;  // 0..3
#pragma unroll
  for (int i = 0; i < 16; ++i) {
    int f = i * 4 + ty;
    tile[f][tx] = Wl[(size_t)(tf * 64 + f) * F + tg * 64 + tx];
  }
  __syncthreads();
#pragma unroll
  for (int i = 0; i < 16; ++i) {
    int g = i * 4 + ty;
    Ol[(size_t)(tg * 64 + g) * F + tf * 64 + tx] = (bf16_t)tile[tx][g];
  }
}

// ---- pre-pass 2: Wlil fp32 -> bf16 (already [m][g][f] = B^T layout)
__global__ void convert_w(const float4* __restrict__ in, bf16x4* __restrict__ out, int n4) {
  int stride = gridDim.x * blockDim.x;
  for (int i = blockIdx.x * blockDim.x + threadIdx.x; i < n4; i += stride) {
    float4 v = in[i];
    bf16x4 o;
    o[0] = (bf16_t)v.x; o[1] = (bf16_t)v.y; o[2] = (bf16_t)v.z; o[3] = (bf16_t)v.w;
    out[i] = o;
  }
}

// ---- main: persistent per-row-block 8-layer MLP chain, activations in LDS ----
// 256 blocks (1/CU): 128 big row-blocks + 8 lil models x 16 row-blocks.
// 512 threads = 8 waves; wave w owns output cols [w*64, w*64+64) over all 128 rows:
// 8 m-tiles x 4 n-tiles of mfma_f32_16x16x32_bf16 -> 128 acc VGPRs.
template <bool PREP>
__global__ __launch_bounds__(512, 2) void fused_mlp(
    const float* __restrict__ x,
    const bf16_t* __restrict__ WbigT, const bf16_t* __restrict__ WlilT,
    const float* __restrict__ WbigF, const float* __restrict__ WlilF,
    const float* __restrict__ Bbig, const float* __restrict__ Blil,
    float* __restrict__ out) {
  __shared__ alignas(16) bf16_t Y[TM * LSTR];

  const int tid = threadIdx.x;
  const int lane = tid & 63;
  const int wave = tid >> 6;        // 0..7
  const int ln15 = lane & 15;
  const int kq = (lane >> 4) << 3;  // 0,8,16,24: quad's k offset within K=32
  const int rq = (lane >> 4) << 2;  // quad's row offset in C tile
  const int col0 = wave * 64;

  // XCD-aware block->(model,row_block): lil model m's 16 blocks pinned to XCD m,
  // so per-XCD L2 W working set per layer ~= 1 MB (big W + one lil W).
  const int bid = blockIdx.x;
  const int xcd = bid & 7;
  const int slot = bid >> 3;
  int model, rb;
  if (slot < 16) { model = 1 + xcd; rb = slot; }
  else           { model = 0; rb = (xcd << 4) + (slot - 16); }

  const size_t grow = (model == 0) ? (size_t)rb * TM
                                   : (size_t)(16384 + (model - 1) * 2048 + rb * TM);

  // ---- stage x tile (fp32 global) into LDS as bf16 ----
  {
    const float4* xs = (const float4*)(x + grow * F);
#pragma unroll
    for (int i = 0; i < 32; ++i) {
      int f4 = tid + i * 512;  // 0..16383
      int row = f4 >> 7;
      int c4 = f4 & 127;
      float4 v = xs[f4];
      bf16x4 o;
      o[0] = (bf16_t)v.x; o[1] = (bf16_t)v.y; o[2] = (bf16_t)v.z; o[3] = (bf16_t)v.w;
      *(bf16x4*)&Y[row * LSTR + c4 * 4] = o;
    }
  }
  __syncthreads();

  for (int l = 0; l < NLAYERS; ++l) {
    const bf16_t* Wt = nullptr;
    const float* Wf = nullptr;
    if (PREP)
      Wt = (model == 0) ? WbigT + (size_t)l * F * F
                        : WlilT + (size_t)(l * NLIL + (model - 1)) * F * F;
    else
      Wf = (model == 0) ? WbigF + (size_t)l * F * F
                        : WlilF + (size_t)(l * NLIL + (model - 1)) * F * F;
    const float* Bp = (model == 0) ? Bbig + (size_t)l * F
                                   : Blil + (size_t)(l * NLIL + (model - 1)) * F;

    // bias is per-col: all 4 C regs and all m-tiles share it -> init acc with bias
    f32x4 acc[8][4];
#pragma unroll
    for (int ni = 0; ni < 4; ++ni) {
      float bv = Bp[col0 + ni * 16 + ln15];
      f32x4 bi = {bv, bv, bv, bv};
#pragma unroll
      for (int mi = 0; mi < 8; ++mi) acc[mi][ni] = bi;
    }

#pragma unroll 2
    for (int ks = 0; ks < 16; ++ks) {
      const int kk = ks * 32 + kq;
      bf16x8 a[8];
#pragma unroll
      for (int mi = 0; mi < 8; ++mi)
        a[mi] = *(const bf16x8*)&Y[(mi * 16 + ln15) * LSTR + kk];
      bf16x8 b[4];
      if (PREP) {
#pragma unroll
        for (int ni = 0; ni < 4; ++ni)
          b[ni] = *(const bf16x8*)&Wt[(size_t)(col0 + ni * 16 + ln15) * F + kk];
      } else if (model != 0) {
        // fallback: fp32 Wlil is [g][f] -> contiguous 8 floats, convert on the fly
#pragma unroll
        for (int ni = 0; ni < 4; ++ni) {
          const float* p = Wf + (size_t)(col0 + ni * 16 + ln15) * F + kk;
          float4 u = *(const float4*)p;
          float4 v = *(const float4*)(p + 4);
          bf16x8 t;
          t[0] = (bf16_t)u.x; t[1] = (bf16_t)u.y; t[2] = (bf16_t)u.z; t[3] = (bf16_t)u.w;
          t[4] = (bf16_t)v.x; t[5] = (bf16_t)v.y; t[6] = (bf16_t)v.z; t[7] = (bf16_t)v.w;
          b[ni] = t;
        }
      } else {
        // fallback: fp32 Wbig is [f][g] -> strided scalar gathers (slow, correct)
#pragma unroll
        for (int ni = 0; ni < 4; ++ni) {
          int col = col0 + ni * 16 + ln15;
          bf16x8 t;
#pragma unroll
          for (int j = 0; j < 8; ++j) t[j] = (bf16_t)Wf[(size_t)(kk + j) * F + col];
          b[ni] = t;
        }
      }
#pragma unroll
      for (int mi = 0; mi < 8; ++mi)
#pragma unroll
        for (int ni = 0; ni < 4; ++ni)
          acc[mi][ni] = __builtin_amdgcn_mfma_f32_16x16x32_bf16(a[mi], b[ni], acc[mi][ni], 0, 0, 0);
    }
    __syncthreads();  // all waves done READING Y before anyone overwrites it

    if (l < NLAYERS - 1) {
      // C/D layout: col = lane&15, row = quad*4 + reg (guide §3, m89-verified)
#pragma unroll
      for (int mi = 0; mi < 8; ++mi)
#pragma unroll
        for (int ni = 0; ni < 4; ++ni) {
          int row = mi * 16 + rq;
          int col = col0 + ni * 16 + ln15;
#pragma unroll
          for (int r = 0; r < 4; ++r)
            Y[(row + r) * LSTR + col] = (bf16_t)acc[mi][ni][r];
        }
      __syncthreads();
    } else {
      // last layer: write fp32 straight to output (skip LDS + extra rounding)
      float* op = out + grow * F;
#pragma unroll
      for (int mi = 0; mi < 8; ++mi)
#pragma unroll
        for (int ni = 0; ni < 4; ++ni) {
          int row = mi * 16 + rq;
          int col = col0 + ni * 16 + ln15;
#pragma unroll
          for (int r = 0; r < 4; ++r)
            op[(size_t)(row + r) * F + col] = acc[mi][ni][r];
        }
    }
  }
}

extern "C" void kernel_launch(void* const* d_in, const int* in_sizes, int n_in,
                              void* d_out, int out_size, void* d_ws, size_t ws_size,
                              hipStream_t stream) {
  const float* x    = (const float*)d_in[0];
  const float* Wbig = (const float*)d_in[1];
  const float* Bbig = (const float*)d_in[2];
  const float* Wlil = (const float*)d_in[3];
  const float* Blil = (const float*)d_in[4];
  float* out = (float*)d_out;

  const size_t nWbig = (size_t)NLAYERS * F * F;         // 2,097,152
  const size_t nWlil = (size_t)NLAYERS * NLIL * F * F;  // 16,777,216
  const size_t need = (nWbig + nWlil) * sizeof(bf16_t); // ~36 MB

  if (ws_size >= need) {
    bf16_t* WbigT = (bf16_t*)d_ws;
    bf16_t* WlilB = WbigT + nWbig;
    transpose_wbig<<<dim3(8, 8, NLAYERS), 256, 0, stream>>>(Wbig, WbigT);
    convert_w<<<4096, 256, 0, stream>>>((const float4*)Wlil, (bf16x4*)WlilB,
                                        (int)(nWlil / 4));
    fused_mlp<true><<<256, 512, 0, stream>>>(x, WbigT, WlilB, nullptr, nullptr,
                                             Bbig, Blil, out);
  } else {
    fused_mlp<false><<<256, 512, 0, stream>>>(x, nullptr, nullptr, Wbig, Wlil,
                                              Bbig, Blil, out);
  }
}

// Round 2
// 329.263 us; speedup vs baseline: 1.0358x; 1.0358x over previous
//
#include <hip/hip_runtime.h>

typedef __bf16 bf16_t;
typedef bf16_t bf16x8 __attribute__((ext_vector_type(8)));
typedef bf16_t bf16x4 __attribute__((ext_vector_type(4)));
typedef float f32x4 __attribute__((ext_vector_type(4)));

#define F 512
#define NLAYERS 8
#define NLIL 8
#define TM 128

// ---- pre-pass 1: Wbig [l][f][g] fp32 -> WbigT [l][g][f] bf16 (transpose+convert)
__global__ void transpose_wbig(const float* __restrict__ W, bf16_t* __restrict__ out) {
  __shared__ float tile[64][65];
  const int l = blockIdx.z;
  const int tf = blockIdx.x, tg = blockIdx.y;
  const float* Wl = W + (size_t)l * F * F;
  bf16_t* Ol = out + (size_t)l * F * F;
  const int tx = threadIdx.x & 63;
  const int ty = threadIdx.x >> 6;  // 0..3
#pragma unroll
  for (int i = 0; i < 16; ++i) {
    int f = i * 4 + ty;
    tile[f][tx] = Wl[(size_t)(tf * 64 + f) * F + tg * 64 + tx];
  }
  __syncthreads();
#pragma unroll
  for (int i = 0; i < 16; ++i) {
    int g = i * 4 + ty;
    Ol[(size_t)(tg * 64 + g) * F + tf * 64 + tx] = (bf16_t)tile[tx][g];
  }
}

// ---- pre-pass 2: Wlil fp32 -> bf16 (already [m][g][f] = B^T layout)
__global__ void convert_w(const float4* __restrict__ in, bf16x4* __restrict__ out, int n4) {
  int stride = gridDim.x * blockDim.x;
  for (int i = blockIdx.x * blockDim.x + threadIdx.x; i < n4; i += stride) {
    float4 v = in[i];
    bf16x4 o;
    o[0] = (bf16_t)v.x; o[1] = (bf16_t)v.y; o[2] = (bf16_t)v.z; o[3] = (bf16_t)v.w;
    out[i] = o;
  }
}

// Swizzled LDS element index for activation Y[m][k] (TM x 512 bf16, no pad):
// 16B chunks along k, chunk index XOR (m&7). Row stride 1024B === 0 mod 128B,
// so the XOR provides the phase stagger a +8 pad used to.
__device__ __forceinline__ int ysw(int m, int k) {
  return m * F + ((((k >> 3) ^ (m & 7)) << 3) | (k & 7));
}

// ---- main: persistent per-row-block 8-layer MLP chain, activations in LDS ----
// 256 blocks (1/CU): 128 big row-blocks + 8 lil models x 16 row-blocks.
// 1024 threads = 16 waves (4/SIMD); wave w owns output cols [w*32, w*32+32):
// 2 g-tiles x 8 m-tiles of mfma(A=W-frag, B=Y-frag) -> 64 acc VGPRs.
// Swapped operands put D's reg axis along g => bf16x4 LDS epilogue writes and
// float4 global stores.
template <bool PREP>
__global__ __launch_bounds__(1024, 4) void fused_mlp(
    const float* __restrict__ x,
    const bf16_t* __restrict__ WbigT, const bf16_t* __restrict__ WlilT,
    const float* __restrict__ WbigF, const float* __restrict__ WlilF,
    const float* __restrict__ Bbig, const float* __restrict__ Blil,
    float* __restrict__ out) {
  __shared__ alignas(16) bf16_t Y[TM * F];  // 128 KB

  const int tid = threadIdx.x;
  const int lane = tid & 63;
  const int wave = tid >> 6;        // 0..15
  const int ln15 = lane & 15;
  const int q = lane >> 4;          // quad 0..3
  const int kq = q << 3;            // quad's k offset within K=32
  const int rq = q << 2;            // quad's offset along D's reg axis (g)
  const int g0 = wave * 32;

  // XCD-aware block->(model,row_block): lil model m's 16 blocks pinned to XCD m.
  const int bid = blockIdx.x;
  const int xcd = bid & 7;
  const int slot = bid >> 3;
  int model, rb;
  if (slot < 16) { model = 1 + xcd; rb = slot; }
  else           { model = 0; rb = (xcd << 4) + (slot - 16); }

  const size_t grow = (model == 0) ? (size_t)rb * TM
                                   : (size_t)(16384 + (model - 1) * 2048 + rb * TM);

  // ---- stage x tile (fp32 global) into LDS as bf16 (swizzled) ----
  {
    const float4* xs = (const float4*)(x + grow * F);
#pragma unroll
    for (int i = 0; i < 16; ++i) {
      int f4 = tid + i * 1024;  // 0..16383
      int row = f4 >> 7;
      int c4 = f4 & 127;
      float4 v = xs[f4];
      bf16x4 o;
      o[0] = (bf16_t)v.x; o[1] = (bf16_t)v.y; o[2] = (bf16_t)v.z; o[3] = (bf16_t)v.w;
      *(bf16x4*)&Y[ysw(row, c4 * 4)] = o;
    }
  }
  __syncthreads();

  for (int l = 0; l < NLAYERS; ++l) {
    const bf16_t* Wt = nullptr;
    const float* Wf = nullptr;
    if (PREP)
      Wt = (model == 0) ? WbigT + (size_t)l * F * F
                        : WlilT + (size_t)(l * NLIL + (model - 1)) * F * F;
    else
      Wf = (model == 0) ? WbigF + (size_t)l * F * F
                        : WlilF + (size_t)(l * NLIL + (model - 1)) * F * F;
    const float* Bp = (model == 0) ? Bbig + (size_t)l * F
                                   : Blil + (size_t)(l * NLIL + (model - 1)) * F;

    // bias is per-g (D's reg axis): one float4 covers reg 0..3; all mi share it
    f32x4 acc[2][8];
#pragma unroll
    for (int gi = 0; gi < 2; ++gi) {
      f32x4 bi = *(const f32x4*)&Bp[g0 + gi * 16 + rq];
#pragma unroll
      for (int mi = 0; mi < 8; ++mi) acc[gi][mi] = bi;
    }

#pragma unroll 2
    for (int ks = 0; ks < 16; ++ks) {
      const int kk = ks * 32 + kq;
      // A-operand: W^T rows (this wave's 32 output cols g), k-contiguous
      bf16x8 aW[2];
      if (PREP) {
#pragma unroll
        for (int gi = 0; gi < 2; ++gi)
          aW[gi] = *(const bf16x8*)&Wt[(size_t)(g0 + gi * 16 + ln15) * F + kk];
      } else if (model != 0) {
#pragma unroll
        for (int gi = 0; gi < 2; ++gi) {
          const float* p = Wf + (size_t)(g0 + gi * 16 + ln15) * F + kk;
          float4 u = *(const float4*)p;
          float4 v = *(const float4*)(p + 4);
          bf16x8 t;
          t[0] = (bf16_t)u.x; t[1] = (bf16_t)u.y; t[2] = (bf16_t)u.z; t[3] = (bf16_t)u.w;
          t[4] = (bf16_t)v.x; t[5] = (bf16_t)v.y; t[6] = (bf16_t)v.z; t[7] = (bf16_t)v.w;
          aW[gi] = t;
        }
      } else {
#pragma unroll
        for (int gi = 0; gi < 2; ++gi) {
          int col = g0 + gi * 16 + ln15;
          bf16x8 t;
#pragma unroll
          for (int j = 0; j < 8; ++j) t[j] = (bf16_t)Wf[(size_t)(kk + j) * F + col];
          aW[gi] = t;
        }
      }
      // B-operand: Y rows, k-contiguous (swizzled chunk)
      bf16x8 bY[8];
      const int chunk = (ks * 4 + q) ^ (ln15 & 7);
#pragma unroll
      for (int mi = 0; mi < 8; ++mi)
        bY[mi] = *(const bf16x8*)&Y[(mi * 16 + ln15) * F + (chunk << 3)];
#pragma unroll
      for (int gi = 0; gi < 2; ++gi)
#pragma unroll
        for (int mi = 0; mi < 8; ++mi)
          acc[gi][mi] = __builtin_amdgcn_mfma_f32_16x16x32_bf16(aW[gi], bY[mi], acc[gi][mi], 0, 0, 0);
    }
    __syncthreads();  // all waves done READING Y before anyone overwrites it

    if (l < NLAYERS - 1) {
      // D layout (operands swapped): lane&15 = m-local, quad*4+reg = g-local
      // => 4 consecutive bf16 along g per lane: one ds_write_b64 per tile
#pragma unroll
      for (int gi = 0; gi < 2; ++gi)
#pragma unroll
        for (int mi = 0; mi < 8; ++mi) {
          int m = mi * 16 + ln15;
          int g = g0 + gi * 16 + rq;
          bf16x4 t;
#pragma unroll
          for (int r = 0; r < 4; ++r) t[r] = (bf16_t)acc[gi][mi][r];
          *(bf16x4*)&Y[ysw(m, g)] = t;  // g%8 in {0,4}: stays inside one chunk
        }
      __syncthreads();
    } else {
      // last layer: coalesced float4 straight to output
      float* op = out + grow * F;
#pragma unroll
      for (int gi = 0; gi < 2; ++gi)
#pragma unroll
        for (int mi = 0; mi < 8; ++mi) {
          int m = mi * 16 + ln15;
          int g = g0 + gi * 16 + rq;
          *(f32x4*)&op[(size_t)m * F + g] = acc[gi][mi];
        }
    }
  }
}

extern "C" void kernel_launch(void* const* d_in, const int* in_sizes, int n_in,
                              void* d_out, int out_size, void* d_ws, size_t ws_size,
                              hipStream_t stream) {
  const float* x    = (const float*)d_in[0];
  const float* Wbig = (const float*)d_in[1];
  const float* Bbig = (const float*)d_in[2];
  const float* Wlil = (const float*)d_in[3];
  const float* Blil = (const float*)d_in[4];
  float* out = (float*)d_out;

  const size_t nWbig = (size_t)NLAYERS * F * F;         // 2,097,152
  const size_t nWlil = (size_t)NLAYERS * NLIL * F * F;  // 16,777,216
  const size_t need = (nWbig + nWlil) * sizeof(bf16_t); // ~36 MB

  if (ws_size >= need) {
    bf16_t* WbigT = (bf16_t*)d_ws;
    bf16_t* WlilB = WbigT + nWbig;
    transpose_wbig<<<dim3(8, 8, NLAYERS), 256, 0, stream>>>(Wbig, WbigT);
    convert_w<<<4096, 256, 0, stream>>>((const float4*)Wlil, (bf16x4*)WlilB,
                                        (int)(nWlil / 4));
    fused_mlp<true><<<256, 1024, 0, stream>>>(x, WbigT, WlilB, nullptr, nullptr,
                                              Bbig, Blil, out);
  } else {
    fused_mlp<false><<<256, 1024, 0, stream>>>(x, nullptr, nullptr, Wbig, Wlil,
                                               Bbig, Blil, out);
  }
}